// Round 18
// baseline (189.045 us; speedup 1.0000x reference)
//
#include <hip/hip_runtime.h>
#include <hip/hip_cooperative_groups.h>

namespace cg = cooperative_groups;

#define NN 50000
#define NE 800000
#define FDIM 64
#define NB 8          // coarse buckets == XCDs
#define P1B 768       // pass-1 blocks (block-private regions)
#define RCAP 256      // per (bucket, block) region capacity (+11.7 sigma)
#define CAP 64        // per-node erow slots
#define OVFCAP 16384
#define NPX 6250      // nodes per XCD range (50000/8)
#define GEMMB ((NN + 63) / 64)   // 782 gemm tiles
#define E4 (NE / 4)              // 200000
#define CHUNK4 ((E4 + P1B - 1) / P1B)   // 261 int4 per partition block
#define FGB 768       // cooperative fill+gather blocks (3/CU co-resident)

typedef float f32x4 __attribute__((ext_vector_type(4)));

__device__ __forceinline__ unsigned rne_bf16(float f) {
    unsigned u = __float_as_uint(f);
    return (u + 0x7fffu + ((u >> 16) & 1u)) >> 16;
}

// ---- fused: blocks [0,P1B) partition; blocks [P1B, P1B+GEMMB) gemm ---------
// (round-17 structure, unchanged: 79.7us total, no VGPR balloon)
__global__ __launch_bounds__(256) void k_part_gemm(
        const int4* __restrict__ row4, const int4* __restrict__ col4,
        unsigned* __restrict__ buckets, int* __restrict__ bcnt,
        int* __restrict__ cnt, unsigned* __restrict__ ovf, int* __restrict__ ovfcnt,
        const float* __restrict__ x, const float* __restrict__ W,
        unsigned* __restrict__ z) {
    __shared__ float Xl[64][68];
    __shared__ float Wt[64][68];   // Wt[k][o]; partition reuses Wt[0][0..7] as lcnt
    int tid = threadIdx.x;

    if (blockIdx.x < P1B) {
        // ---------------- partition ----------------
        int* lcnt = (int*)&Wt[0][0];
        int gid = blockIdx.x * 256 + tid;
        for (int i = gid; i < NN; i += P1B * 256) cnt[i] = 0;
        if (gid == 0) *ovfcnt = 0;

        if (tid < NB) lcnt[tid] = 0;
        __syncthreads();

        int start = blockIdx.x * CHUNK4;
        int end   = min(start + CHUNK4, E4);
        for (int i = start + tid; i < end; i += 256) {
            int4 r4 = row4[i];
            int4 c4 = col4[i];
            int rr[4] = {r4.x, r4.y, r4.z, r4.w};
            int cc[4] = {c4.x, c4.y, c4.z, c4.w};
#pragma unroll
            for (int t = 0; t < 4; ++t) {
                int c = cc[t];
                int bk = (int)(((unsigned long long)(unsigned)c * 687195ull) >> 32); // c/6250
                unsigned pk = ((unsigned)rr[t] << 16) | (unsigned)c;
                int slot = atomicAdd(&lcnt[bk], 1);            // LDS atomic
                if (slot < RCAP)
                    buckets[(size_t)(bk * P1B + blockIdx.x) * RCAP + slot] = pk;
                else {                                         // +11.7 sigma, guarded
                    int o = atomicAdd(ovfcnt, 1);
                    if (o >= 0 && o < OVFCAP) ovf[o] = pk;     // sign-guard vs poison
                }
            }
        }
        __syncthreads();
        if (tid < NB)
            bcnt[tid * P1B + blockIdx.x] = min(lcnt[tid], RCAP);
    } else {
        // ---------------- gemm tile (unroll-1 k4 loop) ----------------
        for (int i = tid; i < FDIM * FDIM; i += 256) {
            int o = i >> 6, k = i & 63;
            Wt[k][o] = W[i];
        }
        int tile = (int)(blockIdx.x - P1B) * 64;
        for (int i = tid; i < 64 * 16; i += 256) {
            int r = i >> 4, c4 = i & 15;
            int gr = tile + r;
            f32x4 v = (gr < NN) ? ((const f32x4*)x)[gr * 16 + c4]
                                : (f32x4){0.f, 0.f, 0.f, 0.f};
            *(f32x4*)&Xl[r][c4 * 4] = v;
        }
        __syncthreads();

        int tr = tid >> 4;
        int tc = tid & 15;

        float acc[4][4] = {};
#pragma unroll 1
        for (int k4 = 0; k4 < 16; ++k4) {
            f32x4 a[4], b[4];
#pragma unroll
            for (int i = 0; i < 4; ++i)
                a[i] = *(const f32x4*)&Xl[tr * 4 + i][k4 * 4];
#pragma unroll
            for (int kk = 0; kk < 4; ++kk)
                b[kk] = *(const f32x4*)&Wt[k4 * 4 + kk][tc * 4];
#pragma unroll
            for (int i = 0; i < 4; ++i) {
#pragma unroll
                for (int jj = 0; jj < 4; ++jj) {
                    acc[i][jj] += a[i].x * b[0][jj] + a[i].y * b[1][jj]
                                + a[i].z * b[2][jj] + a[i].w * b[3][jj];
                }
            }
        }

#pragma unroll
        for (int i = 0; i < 4; ++i) {
            int gr = tile + tr * 4 + i;
            if (gr < NN) {
                unsigned u01 = rne_bf16(acc[i][0]) | (rne_bf16(acc[i][1]) << 16);
                unsigned u23 = rne_bf16(acc[i][2]) | (rne_bf16(acc[i][3]) << 16);
                ((uint2*)z)[gr * 16 + tc] = make_uint2(u01, u23);
            }
        }
    }
}

// ---- cooperative fill + grid.sync + gather ---------------------------------
// Both phases register-light (no GEMM branch -> no round-16 VGPR squeeze).
// 768 blocks, no LDS: 3 blocks/CU co-resident.
__global__ __launch_bounds__(256) void k_fill_gather(
        const unsigned* __restrict__ buckets, const int* __restrict__ bcnt,
        int* __restrict__ cnt, unsigned short* __restrict__ erow,
        const unsigned* __restrict__ z, const float* __restrict__ bias,
        unsigned* __restrict__ ovf, int* __restrict__ ovfcnt,
        float* __restrict__ out) {
    cg::grid_group grid = cg::this_grid();
    int b   = blockIdx.x;
    int tid = threadIdx.x;
    int k   = b & (NB - 1);            // bucket == (assumed) XCD

    // ================= phase 1: fill (8 regions per block) =================
#pragma unroll 1
    for (int j = 0; j < 8; ++j) {
        int b1 = (b >> 3) + (FGB / NB) * j;         // 96-stride
        int m  = bcnt[k * P1B + b1];
        if (tid < m) {                              // m <= RCAP == blockDim
            unsigned pk = buckets[(size_t)(k * P1B + b1) * RCAP + tid];
            int c = (int)(pk & 0xffffu), r = (int)(pk >> 16);
            int p = atomicAdd(&cnt[c], 1);          // doubles as degree count
            if (p < CAP) erow[c * CAP + p] = (unsigned short)r;
            else {                                  // deg > 64: impossible, guarded
                int o = atomicAdd(ovfcnt, 1);
                if (o >= 0 && o < OVFCAP) ovf[o] = pk;
            }
        }
    }

    grid.sync();   // cnt/erow visible to all blocks

    // ================= phase 2: gather =================
    {
        int lane = tid & 63;
        int wv   = tid >> 6;
        int grp  = lane >> 3, sl = lane & 7;
        const uint4* z4 = (const uint4*)z;
        int ovn = min(*ovfcnt, OVFCAP);

#pragma unroll 1
        for (int loc = (b >> 3) * 4 + wv; loc < NPX; loc += (FGB / NB) * 4) {
            int node = k * NPX + loc;
            int d  = cnt[node];
            int dc = min(d, CAP);
            int idx = (lane < dc) ? (int)erow[node * CAP + lane] : 0;

            float a0=0,a1=0,a2=0,a3=0,a4=0,a5=0,a6=0,a7=0;
            int octets = (dc + 7) >> 3;
            for (int j = 0; j < octets; ++j) {
                int ei = j * 8 + grp;
                int rr = __shfl(idx, ei, 64);
                if (ei < dc) {                      // exec-masked
                    int dr = cnt[rr];
                    float sr = (dr > 0) ? rsqrtf((float)dr) : 0.f;
                    uint4 u = z4[rr * 8 + sl];
                    a0 += sr * __uint_as_float(u.x << 16);
                    a1 += sr * __uint_as_float(u.x & 0xffff0000u);
                    a2 += sr * __uint_as_float(u.y << 16);
                    a3 += sr * __uint_as_float(u.y & 0xffff0000u);
                    a4 += sr * __uint_as_float(u.z << 16);
                    a5 += sr * __uint_as_float(u.z & 0xffff0000u);
                    a6 += sr * __uint_as_float(u.w << 16);
                    a7 += sr * __uint_as_float(u.w & 0xffff0000u);
                }
            }

            if (ovn > 0) {                          // impossible path, guarded
                for (int i = 0; i < ovn; ++i) {
                    unsigned pk = ovf[i];
                    if ((int)(pk & 0xffffu) == node && grp == 0) {
                        int rr = (int)(pk >> 16);
                        int dr = cnt[rr];
                        float sr = (dr > 0) ? rsqrtf((float)dr) : 0.f;
                        uint4 u = z4[rr * 8 + sl];
                        a0 += sr * __uint_as_float(u.x << 16);
                        a1 += sr * __uint_as_float(u.x & 0xffff0000u);
                        a2 += sr * __uint_as_float(u.y << 16);
                        a3 += sr * __uint_as_float(u.y & 0xffff0000u);
                        a4 += sr * __uint_as_float(u.z << 16);
                        a5 += sr * __uint_as_float(u.z & 0xffff0000u);
                        a6 += sr * __uint_as_float(u.w << 16);
                        a7 += sr * __uint_as_float(u.w & 0xffff0000u);
                    }
                }
            }

#pragma unroll
            for (int m = 8; m <= 32; m <<= 1) {
                a0 += __shfl_xor(a0, m, 64); a1 += __shfl_xor(a1, m, 64);
                a2 += __shfl_xor(a2, m, 64); a3 += __shfl_xor(a3, m, 64);
                a4 += __shfl_xor(a4, m, 64); a5 += __shfl_xor(a5, m, 64);
                a6 += __shfl_xor(a6, m, 64); a7 += __shfl_xor(a7, m, 64);
            }
            if (grp == 0) {
                float sc = (d > 0) ? rsqrtf((float)d) : 0.f;
                f32x4 b0 = ((const f32x4*)bias)[sl * 2];
                f32x4 b1 = ((const f32x4*)bias)[sl * 2 + 1];
                f32x4 o0 = {sc*a0+b0.x, sc*a1+b0.y, sc*a2+b0.z, sc*a3+b0.w};
                f32x4 o1 = {sc*a4+b1.x, sc*a5+b1.y, sc*a6+b1.z, sc*a7+b1.w};
                __builtin_nontemporal_store(o0, &((f32x4*)out)[node * 16 + sl * 2]);
                __builtin_nontemporal_store(o1, &((f32x4*)out)[node * 16 + sl * 2 + 1]);
            }
        }
    }
}

// ---------------------------------------------------------------------------
extern "C" void kernel_launch(void* const* d_in, const int* in_sizes, int n_in,
                              void* d_out, int out_size, void* d_ws, size_t ws_size,
                              hipStream_t stream) {
    const float* x   = (const float*)d_in[0];
    // d_in[1] = x0 (unused: use_init=False)
    const int*   ei  = (const int*)d_in[2];   // harness stores integers as int32
    const float* W_w = (const float*)d_in[3];
    const float* W_b = (const float*)d_in[4];
    float*       out = (float*)d_out;

    const int4* row4 = (const int4*)ei;          // edge_index[0]
    const int4* col4 = (const int4*)(ei + NE);   // edge_index[1]

    char* p = (char*)d_ws;
    auto alloc = [&](size_t bytes) {
        char* r = p;
        p += (bytes + 255) & ~(size_t)255;
        return r;
    };
    int*            cnt     = (int*)alloc(NN * sizeof(int));
    int*            ovfcnt  = (int*)alloc(256);
    unsigned*       ovf     = (unsigned*)alloc(OVFCAP * sizeof(unsigned));
    int*            bcnt    = (int*)alloc(NB * P1B * sizeof(int));
    unsigned short* erow    = (unsigned short*)alloc((size_t)NN * CAP * sizeof(unsigned short));
    unsigned*       buckets = (unsigned*)alloc((size_t)NB * P1B * RCAP * sizeof(unsigned)); // 6.3 MB
    unsigned*       z       = (unsigned*)alloc((size_t)NN * FDIM * 2);                      // 6.4 MB

    k_part_gemm<<<P1B + GEMMB, 256, 0, stream>>>(row4, col4, buckets, bcnt, cnt,
                                                 ovf, ovfcnt, x, W_w, z);

    void* args[] = {(void*)&buckets, (void*)&bcnt, (void*)&cnt, (void*)&erow,
                    (void*)&z, (void*)&W_b, (void*)&ovf, (void*)&ovfcnt, (void*)&out};
    (void)hipLaunchCooperativeKernel((const void*)k_fill_gather, dim3(FGB), dim3(256),
                                     args, 0, stream);
}

// Round 19
// 79.936 us; speedup vs baseline: 2.3650x; 2.3650x over previous
//
#include <hip/hip_runtime.h>

#define NN 50000
#define NE 800000
#define FDIM 64
#define NB 8          // coarse buckets == XCDs
#define P1B 768       // pass-1 blocks (block-private regions)
#define RCAP 256      // per (bucket, block) region capacity (+11.7 sigma)
#define CAP 64        // per-node erow slots
#define OVFCAP 16384
#define NPX 6250      // nodes per XCD range (50000/8)
#define GEMMB ((NN + 63) / 64)   // 782 gemm tiles
#define E4 (NE / 4)              // 200000
#define CHUNK4 ((E4 + P1B - 1) / P1B)   // 261 int4 per partition block
#define FB 768        // fill blocks: 8 regions each (was 6144 one-shot blocks)

typedef float f32x4 __attribute__((ext_vector_type(4)));

__device__ __forceinline__ unsigned rne_bf16(float f) {
    unsigned u = __float_as_uint(f);
    return (u + 0x7fffu + ((u >> 16) & 1u)) >> 16;
}

// ---- fused: blocks [0,P1B) partition; blocks [P1B, P1B+GEMMB) gemm ---------
// (round-17 structure, unchanged: best known, no VGPR balloon)
__global__ __launch_bounds__(256) void k_part_gemm(
        const int4* __restrict__ row4, const int4* __restrict__ col4,
        unsigned* __restrict__ buckets, int* __restrict__ bcnt,
        int* __restrict__ cnt, unsigned* __restrict__ ovf, int* __restrict__ ovfcnt,
        const float* __restrict__ x, const float* __restrict__ W,
        unsigned* __restrict__ z) {
    __shared__ float Xl[64][68];
    __shared__ float Wt[64][68];   // Wt[k][o]; partition reuses Wt[0][0..7] as lcnt
    int tid = threadIdx.x;

    if (blockIdx.x < P1B) {
        // ---------------- partition ----------------
        int* lcnt = (int*)&Wt[0][0];
        int gid = blockIdx.x * 256 + tid;
        for (int i = gid; i < NN; i += P1B * 256) cnt[i] = 0;
        if (gid == 0) *ovfcnt = 0;

        if (tid < NB) lcnt[tid] = 0;
        __syncthreads();

        int start = blockIdx.x * CHUNK4;
        int end   = min(start + CHUNK4, E4);
        for (int i = start + tid; i < end; i += 256) {
            int4 r4 = row4[i];
            int4 c4 = col4[i];
            int rr[4] = {r4.x, r4.y, r4.z, r4.w};
            int cc[4] = {c4.x, c4.y, c4.z, c4.w};
#pragma unroll
            for (int t = 0; t < 4; ++t) {
                int c = cc[t];
                int bk = (int)(((unsigned long long)(unsigned)c * 687195ull) >> 32); // c/6250
                unsigned pk = ((unsigned)rr[t] << 16) | (unsigned)c;
                int slot = atomicAdd(&lcnt[bk], 1);            // LDS atomic
                if (slot < RCAP)
                    buckets[(size_t)(bk * P1B + blockIdx.x) * RCAP + slot] = pk;
                else {                                         // +11.7 sigma, guarded
                    int o = atomicAdd(ovfcnt, 1);
                    if (o >= 0 && o < OVFCAP) ovf[o] = pk;     // sign-guard vs poison
                }
            }
        }
        __syncthreads();
        if (tid < NB)
            bcnt[tid * P1B + blockIdx.x] = min(lcnt[tid], RCAP);
    } else {
        // ---------------- gemm tile (unroll-1 k4 loop) ----------------
        for (int i = tid; i < FDIM * FDIM; i += 256) {
            int o = i >> 6, k = i & 63;
            Wt[k][o] = W[i];
        }
        int tile = (int)(blockIdx.x - P1B) * 64;
        for (int i = tid; i < 64 * 16; i += 256) {
            int r = i >> 4, c4 = i & 15;
            int gr = tile + r;
            f32x4 v = (gr < NN) ? ((const f32x4*)x)[gr * 16 + c4]
                                : (f32x4){0.f, 0.f, 0.f, 0.f};
            *(f32x4*)&Xl[r][c4 * 4] = v;
        }
        __syncthreads();

        int tr = tid >> 4;
        int tc = tid & 15;

        float acc[4][4] = {};
#pragma unroll 1
        for (int k4 = 0; k4 < 16; ++k4) {
            f32x4 a[4], b[4];
#pragma unroll
            for (int i = 0; i < 4; ++i)
                a[i] = *(const f32x4*)&Xl[tr * 4 + i][k4 * 4];
#pragma unroll
            for (int kk = 0; kk < 4; ++kk)
                b[kk] = *(const f32x4*)&Wt[k4 * 4 + kk][tc * 4];
#pragma unroll
            for (int i = 0; i < 4; ++i) {
#pragma unroll
                for (int jj = 0; jj < 4; ++jj) {
                    acc[i][jj] += a[i].x * b[0][jj] + a[i].y * b[1][jj]
                                + a[i].z * b[2][jj] + a[i].w * b[3][jj];
                }
            }
        }

#pragma unroll
        for (int i = 0; i < 4; ++i) {
            int gr = tile + tr * 4 + i;
            if (gr < NN) {
                unsigned u01 = rne_bf16(acc[i][0]) | (rne_bf16(acc[i][1]) << 16);
                unsigned u23 = rne_bf16(acc[i][2]) | (rne_bf16(acc[i][3]) << 16);
                ((uint2*)z)[gr * 16 + tc] = make_uint2(u01, u23);
            }
        }
    }
}

// ---- pass 2: fill — 768 blocks x 8 regions (fewer scheduling rounds) -------
__global__ __launch_bounds__(256) void k_fill(const unsigned* __restrict__ buckets,
                                              const int* __restrict__ bcnt,
                                              int* __restrict__ cnt,
                                              unsigned short* __restrict__ erow,
                                              unsigned* __restrict__ ovf,
                                              int* __restrict__ ovfcnt) {
    int b   = blockIdx.x;
    int tid = threadIdx.x;
    int k   = b & (NB - 1);            // bucket == (assumed) XCD of this block
#pragma unroll 1
    for (int j = 0; j < 8; ++j) {
        int b1 = (b >> 3) + (FB / NB) * j;          // 96-stride over regions
        int m  = bcnt[k * P1B + b1];
        if (tid < m) {                              // m <= RCAP == 256 == blockDim
            unsigned pk = buckets[(size_t)(k * P1B + b1) * RCAP + tid];
            int c = (int)(pk & 0xffffu), r = (int)(pk >> 16);
            int p = atomicAdd(&cnt[c], 1);          // doubles as degree count
            if (p < CAP) erow[c * CAP + p] = (unsigned short)r;
            else {                                  // deg > 64: impossible, guarded
                int o = atomicAdd(ovfcnt, 1);
                if (o >= 0 && o < OVFCAP) ovf[o] = pk;
            }
        }
    }
}

// ---- gather: wave/node, 8 edges/iter, 8 lanes/edge; per-edge rsqrt scale ---
__global__ __launch_bounds__(256) void k_gather(
        const int* __restrict__ cnt, const unsigned short* __restrict__ erow,
        const uint4* __restrict__ z4, const float* __restrict__ bias,
        const unsigned* __restrict__ ovf, const int* __restrict__ ovfcnt,
        float* __restrict__ out) {
    int lane = threadIdx.x & 63;
    int wv   = threadIdx.x >> 6;
    int xk   = blockIdx.x & 7;          // node range == (assumed) XCD
    int sub  = blockIdx.x >> 3;
    int loc  = sub * 4 + wv;
    if (loc >= NPX) return;
    int node = xk * NPX + loc;

    int d  = cnt[node];
    int dc = min(d, CAP);
    int grp = lane >> 3, sl = lane & 7;
    int idx = (lane < dc) ? (int)erow[node * CAP + lane] : 0;  // masked: 32B avg

    float a0=0,a1=0,a2=0,a3=0,a4=0,a5=0,a6=0,a7=0;
    int octets = (dc + 7) >> 3;
    for (int j = 0; j < octets; ++j) {
        int ei = j * 8 + grp;
        int rr = __shfl(idx, ei, 64);          // uniform control flow for shfl
        if (ei < dc) {                          // exec-masked
            int dr = cnt[rr];                   // 4B broadcast within group, L2-hot
            float sr = (dr > 0) ? rsqrtf((float)dr) : 0.f;
            uint4 u = z4[rr * 8 + sl];
            a0 += sr * __uint_as_float(u.x << 16);
            a1 += sr * __uint_as_float(u.x & 0xffff0000u);
            a2 += sr * __uint_as_float(u.y << 16);
            a3 += sr * __uint_as_float(u.y & 0xffff0000u);
            a4 += sr * __uint_as_float(u.z << 16);
            a5 += sr * __uint_as_float(u.z & 0xffff0000u);
            a6 += sr * __uint_as_float(u.w << 16);
            a7 += sr * __uint_as_float(u.w & 0xffff0000u);
        }
    }

    // overflow drain (impossible path, kept for strict correctness)
    int ovn = min(*ovfcnt, OVFCAP);
    if (ovn > 0) {
        for (int i = 0; i < ovn; ++i) {
            unsigned pk = ovf[i];
            if ((int)(pk & 0xffffu) == node && grp == 0) {
                int rr = (int)(pk >> 16);
                int dr = cnt[rr];
                float sr = (dr > 0) ? rsqrtf((float)dr) : 0.f;
                uint4 u = z4[rr * 8 + sl];
                a0 += sr * __uint_as_float(u.x << 16);
                a1 += sr * __uint_as_float(u.x & 0xffff0000u);
                a2 += sr * __uint_as_float(u.y << 16);
                a3 += sr * __uint_as_float(u.y & 0xffff0000u);
                a4 += sr * __uint_as_float(u.z << 16);
                a5 += sr * __uint_as_float(u.z & 0xffff0000u);
                a6 += sr * __uint_as_float(u.w << 16);
                a7 += sr * __uint_as_float(u.w & 0xffff0000u);
            }
        }
    }

#pragma unroll
    for (int m = 8; m <= 32; m <<= 1) {
        a0 += __shfl_xor(a0, m, 64); a1 += __shfl_xor(a1, m, 64);
        a2 += __shfl_xor(a2, m, 64); a3 += __shfl_xor(a3, m, 64);
        a4 += __shfl_xor(a4, m, 64); a5 += __shfl_xor(a5, m, 64);
        a6 += __shfl_xor(a6, m, 64); a7 += __shfl_xor(a7, m, 64);
    }
    if (grp == 0) {
        float sc = (d > 0) ? rsqrtf((float)d) : 0.f;
        f32x4 b0 = ((const f32x4*)bias)[sl * 2];
        f32x4 b1 = ((const f32x4*)bias)[sl * 2 + 1];
        f32x4 o0 = {sc*a0+b0.x, sc*a1+b0.y, sc*a2+b0.z, sc*a3+b0.w};
        f32x4 o1 = {sc*a4+b1.x, sc*a5+b1.y, sc*a6+b1.z, sc*a7+b1.w};
        __builtin_nontemporal_store(o0, &((f32x4*)out)[node * 16 + sl * 2]);
        __builtin_nontemporal_store(o1, &((f32x4*)out)[node * 16 + sl * 2 + 1]);
    }
}

// ---------------------------------------------------------------------------
extern "C" void kernel_launch(void* const* d_in, const int* in_sizes, int n_in,
                              void* d_out, int out_size, void* d_ws, size_t ws_size,
                              hipStream_t stream) {
    const float* x   = (const float*)d_in[0];
    // d_in[1] = x0 (unused: use_init=False)
    const int*   ei  = (const int*)d_in[2];   // harness stores integers as int32
    const float* W_w = (const float*)d_in[3];
    const float* W_b = (const float*)d_in[4];
    float*       out = (float*)d_out;

    const int4* row4 = (const int4*)ei;          // edge_index[0]
    const int4* col4 = (const int4*)(ei + NE);   // edge_index[1]

    char* p = (char*)d_ws;
    auto alloc = [&](size_t bytes) {
        char* r = p;
        p += (bytes + 255) & ~(size_t)255;
        return r;
    };
    int*            cnt     = (int*)alloc(NN * sizeof(int));
    int*            ovfcnt  = (int*)alloc(256);
    unsigned*       ovf     = (unsigned*)alloc(OVFCAP * sizeof(unsigned));
    int*            bcnt    = (int*)alloc(NB * P1B * sizeof(int));
    unsigned short* erow    = (unsigned short*)alloc((size_t)NN * CAP * sizeof(unsigned short));
    unsigned*       buckets = (unsigned*)alloc((size_t)NB * P1B * RCAP * sizeof(unsigned)); // 6.3 MB
    unsigned*       z       = (unsigned*)alloc((size_t)NN * FDIM * 2);                      // 6.4 MB

    k_part_gemm<<<P1B + GEMMB, 256, 0, stream>>>(row4, col4, buckets, bcnt, cnt,
                                                 ovf, ovfcnt, x, W_w, z);
    k_fill  <<<FB, 256, 0, stream>>>(buckets, bcnt, cnt, erow, ovf, ovfcnt);
    k_gather<<<NB * ((NPX + 3) / 4), 256, 0, stream>>>(cnt, erow, (const uint4*)z, W_b,
                                                       ovf, ovfcnt, out);
}

// Round 20
// 70.970 us; speedup vs baseline: 2.6637x; 1.1263x over previous
//
#include <hip/hip_runtime.h>

#define NN 50000
#define NE 800000
#define FDIM 64
#define NB 8          // coarse buckets == XCDs
#define P1B 768       // pass-1 blocks (block-private regions)
#define RCAP 256      // per (bucket, block) region capacity (+11.7 sigma)
#define CAP 64        // per-node erow slots
#define OVFCAP 16384
#define NPX 6250      // nodes per XCD range (50000/8)
#define GEMMB ((NN + 63) / 64)   // 782 gemm tiles
#define E4 (NE / 4)              // 200000
#define CHUNK4 ((E4 + P1B - 1) / P1B)   // 261 int4 per partition block
#define FB 768        // fill blocks (8 regions each)

typedef float f32x4 __attribute__((ext_vector_type(4)));

__device__ __forceinline__ unsigned rne_bf16(float f) {
    unsigned u = __float_as_uint(f);
    return (u + 0x7fffu + ((u >> 16) & 1u)) >> 16;
}

// ---- dispatch 1: partition alone (tiny LDS -> high occupancy) --------------
__global__ __launch_bounds__(256) void k_part(
        const int4* __restrict__ row4, const int4* __restrict__ col4,
        unsigned* __restrict__ buckets, int* __restrict__ bcnt,
        int* __restrict__ cnt, unsigned* __restrict__ ovf, int* __restrict__ ovfcnt) {
    __shared__ int lcnt[NB];
    int tid = threadIdx.x;
    int gid = blockIdx.x * 256 + tid;
    for (int i = gid; i < NN; i += P1B * 256) cnt[i] = 0;
    if (gid == 0) *ovfcnt = 0;

    if (tid < NB) lcnt[tid] = 0;
    __syncthreads();

    int start = blockIdx.x * CHUNK4;
    int end   = min(start + CHUNK4, E4);
    for (int i = start + tid; i < end; i += 256) {
        int4 r4 = row4[i];
        int4 c4 = col4[i];
        int rr[4] = {r4.x, r4.y, r4.z, r4.w};
        int cc[4] = {c4.x, c4.y, c4.z, c4.w};
#pragma unroll
        for (int t = 0; t < 4; ++t) {
            int c = cc[t];
            int bk = (int)(((unsigned long long)(unsigned)c * 687195ull) >> 32); // c/6250
            unsigned pk = ((unsigned)rr[t] << 16) | (unsigned)c;
            int slot = atomicAdd(&lcnt[bk], 1);            // LDS atomic
            if (slot < RCAP)
                buckets[(size_t)(bk * P1B + blockIdx.x) * RCAP + slot] = pk;
            else {                                         // +11.7 sigma, guarded
                int o = atomicAdd(ovfcnt, 1);
                if (o >= 0 && o < OVFCAP) ovf[o] = pk;     // sign-guard vs poison
            }
        }
    }
    __syncthreads();
    if (tid < NB)
        bcnt[tid * P1B + blockIdx.x] = min(lcnt[tid], RCAP);
}

// ---- dispatch 2: blocks [0,GEMMB) gemm; blocks [GEMMB,+FB) fill ------------
// fill depends only on k_part (done); gemm depends on nothing -> they overlap
// inside one dispatch. Fill is register-light, so no regalloc coupling hazard
// (round-17-proven branch-fusion pattern; rounds 13/16/18 failure modes avoided).
__global__ __launch_bounds__(256) void k_gemm_fill(
        const float* __restrict__ x, const float* __restrict__ W,
        unsigned* __restrict__ z,
        const unsigned* __restrict__ buckets, const int* __restrict__ bcnt,
        int* __restrict__ cnt, unsigned short* __restrict__ erow,
        unsigned* __restrict__ ovf, int* __restrict__ ovfcnt) {
    __shared__ float Xl[64][68];
    __shared__ float Wt[64][68];   // Wt[k][o]
    int tid = threadIdx.x;

    if (blockIdx.x < GEMMB) {
        // ---------------- gemm tile (unroll-1 k4 loop) ----------------
        for (int i = tid; i < FDIM * FDIM; i += 256) {
            int o = i >> 6, k = i & 63;
            Wt[k][o] = W[i];
        }
        int tile = (int)blockIdx.x * 64;
        for (int i = tid; i < 64 * 16; i += 256) {
            int r = i >> 4, c4 = i & 15;
            int gr = tile + r;
            f32x4 v = (gr < NN) ? ((const f32x4*)x)[gr * 16 + c4]
                                : (f32x4){0.f, 0.f, 0.f, 0.f};
            *(f32x4*)&Xl[r][c4 * 4] = v;
        }
        __syncthreads();

        int tr = tid >> 4;
        int tc = tid & 15;

        float acc[4][4] = {};
#pragma unroll 1
        for (int k4 = 0; k4 < 16; ++k4) {
            f32x4 a[4], b[4];
#pragma unroll
            for (int i = 0; i < 4; ++i)
                a[i] = *(const f32x4*)&Xl[tr * 4 + i][k4 * 4];
#pragma unroll
            for (int kk = 0; kk < 4; ++kk)
                b[kk] = *(const f32x4*)&Wt[k4 * 4 + kk][tc * 4];
#pragma unroll
            for (int i = 0; i < 4; ++i) {
#pragma unroll
                for (int jj = 0; jj < 4; ++jj) {
                    acc[i][jj] += a[i].x * b[0][jj] + a[i].y * b[1][jj]
                                + a[i].z * b[2][jj] + a[i].w * b[3][jj];
                }
            }
        }

#pragma unroll
        for (int i = 0; i < 4; ++i) {
            int gr = tile + tr * 4 + i;
            if (gr < NN) {
                unsigned u01 = rne_bf16(acc[i][0]) | (rne_bf16(acc[i][1]) << 16);
                unsigned u23 = rne_bf16(acc[i][2]) | (rne_bf16(acc[i][3]) << 16);
                ((uint2*)z)[gr * 16 + tc] = make_uint2(u01, u23);
            }
        }
    } else {
        // ---------------- fill (8 regions per block) ----------------
        int b2 = (int)blockIdx.x - GEMMB;         // 0..FB-1
        int k  = b2 & (NB - 1);                   // bucket == (assumed) XCD
#pragma unroll 1
        for (int j = 0; j < 8; ++j) {
            int b1 = (b2 >> 3) + (FB / NB) * j;   // 96-stride over regions
            int m  = bcnt[k * P1B + b1];
            if (tid < m) {                        // m <= RCAP == 256 == blockDim
                unsigned pk = buckets[(size_t)(k * P1B + b1) * RCAP + tid];
                int c = (int)(pk & 0xffffu), r = (int)(pk >> 16);
                int p = atomicAdd(&cnt[c], 1);    // doubles as degree count
                if (p < CAP) erow[c * CAP + p] = (unsigned short)r;
                else {                            // deg > 64: impossible, guarded
                    int o = atomicAdd(ovfcnt, 1);
                    if (o >= 0 && o < OVFCAP) ovf[o] = pk;
                }
            }
        }
    }
}

// ---- dispatch 3: gather — wave/node, 8 edges/iter, per-edge rsqrt scale ----
__global__ __launch_bounds__(256) void k_gather(
        const int* __restrict__ cnt, const unsigned short* __restrict__ erow,
        const uint4* __restrict__ z4, const float* __restrict__ bias,
        const unsigned* __restrict__ ovf, const int* __restrict__ ovfcnt,
        float* __restrict__ out) {
    int lane = threadIdx.x & 63;
    int wv   = threadIdx.x >> 6;
    int xk   = blockIdx.x & 7;          // node range == (assumed) XCD
    int sub  = blockIdx.x >> 3;
    int loc  = sub * 4 + wv;
    if (loc >= NPX) return;
    int node = xk * NPX + loc;

    int d  = cnt[node];
    int dc = min(d, CAP);
    int grp = lane >> 3, sl = lane & 7;
    int idx = (lane < dc) ? (int)erow[node * CAP + lane] : 0;  // masked: 32B avg

    float a0=0,a1=0,a2=0,a3=0,a4=0,a5=0,a6=0,a7=0;
    int octets = (dc + 7) >> 3;
    for (int j = 0; j < octets; ++j) {
        int ei = j * 8 + grp;
        int rr = __shfl(idx, ei, 64);          // uniform control flow for shfl
        if (ei < dc) {                          // exec-masked
            int dr = cnt[rr];                   // 4B broadcast within group, L2-hot
            float sr = (dr > 0) ? rsqrtf((float)dr) : 0.f;
            uint4 u = z4[rr * 8 + sl];
            a0 += sr * __uint_as_float(u.x << 16);
            a1 += sr * __uint_as_float(u.x & 0xffff0000u);
            a2 += sr * __uint_as_float(u.y << 16);
            a3 += sr * __uint_as_float(u.y & 0xffff0000u);
            a4 += sr * __uint_as_float(u.z << 16);
            a5 += sr * __uint_as_float(u.z & 0xffff0000u);
            a6 += sr * __uint_as_float(u.w << 16);
            a7 += sr * __uint_as_float(u.w & 0xffff0000u);
        }
    }

    // overflow drain (impossible path, kept for strict correctness)
    int ovn = min(*ovfcnt, OVFCAP);
    if (ovn > 0) {
        for (int i = 0; i < ovn; ++i) {
            unsigned pk = ovf[i];
            if ((int)(pk & 0xffffu) == node && grp == 0) {
                int rr = (int)(pk >> 16);
                int dr = cnt[rr];
                float sr = (dr > 0) ? rsqrtf((float)dr) : 0.f;
                uint4 u = z4[rr * 8 + sl];
                a0 += sr * __uint_as_float(u.x << 16);
                a1 += sr * __uint_as_float(u.x & 0xffff0000u);
                a2 += sr * __uint_as_float(u.y << 16);
                a3 += sr * __uint_as_float(u.y & 0xffff0000u);
                a4 += sr * __uint_as_float(u.z << 16);
                a5 += sr * __uint_as_float(u.z & 0xffff0000u);
                a6 += sr * __uint_as_float(u.w << 16);
                a7 += sr * __uint_as_float(u.w & 0xffff0000u);
            }
        }
    }

#pragma unroll
    for (int m = 8; m <= 32; m <<= 1) {
        a0 += __shfl_xor(a0, m, 64); a1 += __shfl_xor(a1, m, 64);
        a2 += __shfl_xor(a2, m, 64); a3 += __shfl_xor(a3, m, 64);
        a4 += __shfl_xor(a4, m, 64); a5 += __shfl_xor(a5, m, 64);
        a6 += __shfl_xor(a6, m, 64); a7 += __shfl_xor(a7, m, 64);
    }
    if (grp == 0) {
        float sc = (d > 0) ? rsqrtf((float)d) : 0.f;
        f32x4 b0 = ((const f32x4*)bias)[sl * 2];
        f32x4 b1 = ((const f32x4*)bias)[sl * 2 + 1];
        f32x4 o0 = {sc*a0+b0.x, sc*a1+b0.y, sc*a2+b0.z, sc*a3+b0.w};
        f32x4 o1 = {sc*a4+b1.x, sc*a5+b1.y, sc*a6+b1.z, sc*a7+b1.w};
        __builtin_nontemporal_store(o0, &((f32x4*)out)[node * 16 + sl * 2]);
        __builtin_nontemporal_store(o1, &((f32x4*)out)[node * 16 + sl * 2 + 1]);
    }
}

// ---------------------------------------------------------------------------
extern "C" void kernel_launch(void* const* d_in, const int* in_sizes, int n_in,
                              void* d_out, int out_size, void* d_ws, size_t ws_size,
                              hipStream_t stream) {
    const float* x   = (const float*)d_in[0];
    // d_in[1] = x0 (unused: use_init=False)
    const int*   ei  = (const int*)d_in[2];   // harness stores integers as int32
    const float* W_w = (const float*)d_in[3];
    const float* W_b = (const float*)d_in[4];
    float*       out = (float*)d_out;

    const int4* row4 = (const int4*)ei;          // edge_index[0]
    const int4* col4 = (const int4*)(ei + NE);   // edge_index[1]

    char* p = (char*)d_ws;
    auto alloc = [&](size_t bytes) {
        char* r = p;
        p += (bytes + 255) & ~(size_t)255;
        return r;
    };
    int*            cnt     = (int*)alloc(NN * sizeof(int));
    int*            ovfcnt  = (int*)alloc(256);
    unsigned*       ovf     = (unsigned*)alloc(OVFCAP * sizeof(unsigned));
    int*            bcnt    = (int*)alloc(NB * P1B * sizeof(int));
    unsigned short* erow    = (unsigned short*)alloc((size_t)NN * CAP * sizeof(unsigned short));
    unsigned*       buckets = (unsigned*)alloc((size_t)NB * P1B * RCAP * sizeof(unsigned)); // 6.3 MB
    unsigned*       z       = (unsigned*)alloc((size_t)NN * FDIM * 2);                      // 6.4 MB

    k_part     <<<P1B, 256, 0, stream>>>(row4, col4, buckets, bcnt, cnt, ovf, ovfcnt);
    k_gemm_fill<<<GEMMB + FB, 256, 0, stream>>>(x, W_w, z, buckets, bcnt, cnt, erow,
                                                ovf, ovfcnt);
    k_gather   <<<NB * ((NPX + 3) / 4), 256, 0, stream>>>(cnt, erow, (const uint4*)z, W_b,
                                                          ovf, ovfcnt, out);
}